// Round 10
// baseline (403.906 us; speedup 1.0000x reference)
//
#include <hip/hip_runtime.h>
#include <hip/hip_bf16.h>

typedef unsigned short ushort_t;
typedef unsigned int uint_t;

typedef __attribute__((ext_vector_type(8))) short short8;
typedef __attribute__((ext_vector_type(4))) float f32x4;

#define BATCH 512
#define DK    512
#define CTOT  100000
#define BNF   32                  // per-block column tile; CTOT = 3125*32 exact
#define THRESH_C (-0.8775825618903728f)   // cos(pi - 0.5)
#define MM_C     (0.2397127693021015f)    // sin(0.5)*0.5
#define TS_S  35                  // epilogue scratch stride (32 + 3 pad)

// round-to-nearest-even fp32 -> bf16
static __device__ __forceinline__ ushort_t f2bf(float f) {
    union { float f; uint_t u; } v; v.f = f;
    return (ushort_t)((v.u + 0x7FFFu + ((v.u >> 16) & 1u)) >> 16);
}

// ---------------------------------------------------------------------------
// Prep: normalize x rows -> bf16 stored in MFMA-A-fragment-major order:
//   exbF[row_block(32)][ko(16)][lane(64)*8 elems]
//   element (b,k): row_block=b>>4, ko=k>>5, lane=(k>>3&3)*16+(b&15), j=k&7
// Also computes fp32-exact target[b] from cos_lb.
// grid = 512 blocks (one per batch row), 256 threads.
// ---------------------------------------------------------------------------
__global__ __launch_bounds__(256) void arc_prep(
    const float* __restrict__ x, const int* __restrict__ label,
    const float* __restrict__ w, float* __restrict__ target,
    ushort_t* __restrict__ exbF)
{
    const int b = blockIdx.x;
    const int t = threadIdx.x;
    __shared__ float red[8];

    const float2 xv = ((const float2*)(x + (size_t)b * DK))[t];
    float ss = xv.x * xv.x + xv.y * xv.y;
    #pragma unroll
    for (int o = 32; o; o >>= 1) ss += __shfl_xor(ss, o);
    if ((t & 63) == 0) red[t >> 6] = ss;
    __syncthreads();
    const float ssx = red[0] + red[1] + red[2] + red[3];
    const float rnx = 1.0f / sqrtf(ssx);

    {
        const int k = 2 * t;
        const int ko = k >> 5;
        const int qk = (k >> 3) & 3;
        const int kj = k & 7;                       // even
        const size_t F = (size_t)(b >> 4) * 8192 + (size_t)ko * 512
                       + (size_t)qk * 128 + (size_t)(b & 15) * 8 + kj;
        ushort2 e;
        e.x = f2bf(xv.x * rnx);
        e.y = f2bf(xv.y * rnx);
        *(ushort2*)(exbF + F) = e;
    }

    const int lb = label[b];
    const float2 wv = ((const float2*)(w + (size_t)lb * DK))[t];
    float ssw = wv.x * wv.x + wv.y * wv.y;
    float dot = xv.x * wv.x + xv.y * wv.y;
    #pragma unroll
    for (int o = 32; o; o >>= 1) { ssw += __shfl_xor(ssw, o); dot += __shfl_xor(dot, o); }
    __syncthreads();                 // guard red[] reuse
    if ((t & 63) == 0) { red[t >> 6] = ssw; red[4 + (t >> 6)] = dot; }
    __syncthreads();
    if (t == 0) {
        const float sw = red[0] + red[1] + red[2] + red[3];
        const float dt = red[4] + red[5] + red[6] + red[7];
        float cl = dt * rnx / sqrtf(sw);
        cl = fminf(fmaxf(cl, -1.0f), 1.0f);
        const float tg = (cl > THRESH_C) ? cosf(acosf(cl) + 0.5f) : (cl - MM_C);
        target[b] = tg;
    }
}

// ---------------------------------------------------------------------------
// Fused main, BNF=32 / 4-blocks-per-CU edition. r9's verified structure
// (fused stage+convert -> barrier-free K-loop -> transposed full-line NT
// epilogue) with the LDS footprint halved: 32 KB B tile + 1 KB rsum ->
// 4 resident blocks/CU (r9's 66 KB allowed only 2, and the 3-phase barrier
// convoy couldn't interleave across 2 blocks: occ 36%, dur 139us, nothing
// saturated). 4 independent blocks per CU let staging / MFMA / NT-store
// phases overlap. CTOT = 3125*32 exactly -> grid 3125, zero predication.
//
// Staging: thread t, iter i (0..3) writes LDS ushort off i*4096 + t*8 =
// rb*8192 + ko*512 + qk*128 + colq*8 with rb=i>>1, ko=(i&1)*8+wid -> row
// c0 + rb*16 + colq, k = ko*32 + qk*8..+8: 2x NT dwordx4 (each W line read
// exactly once; don't evict exbF from L2). Per-class sumsq: lane partials
// -> shfl_xor 16/32 -> rsum[wid][32] -> 32-thread fold to 1/sqrt.
//
// K-loop: A-frags from L2-resident exbF (512 KB, shared by all blocks),
// B via ds_read_b128, 16 ko x 8 MFMA, acc[4][2] (AGPRs).
// Epilogue: per-wave 16x35 f32 scratch in dead Bs; write logits (dword),
// lgkmcnt(0), read back 8-rows-per-instr (lane -> row lane>>3, cols
// (lane&7)*4) -> NT f32x4 = full 64B lines (amp 1.00 verified r9).
// ---------------------------------------------------------------------------
__global__ __launch_bounds__(512, 8) void arc_fused(
    const ushort_t* __restrict__ exbF, const float* __restrict__ w,
    const int* __restrict__ label, const float* __restrict__ target,
    float* __restrict__ out)
{
    __shared__ ushort_t Bs[2 * 8192];  // 32 KB: B tile, then f32 scratch
    __shared__ float    rsum[8 * 32];  // per-wave sumsq partials; row0 -> rn

    const int t    = threadIdx.x;
    const int lane = t & 63;
    const int wid  = t >> 6;           // 0..7 row-group / ko-group
    const int c0   = blockIdx.x * BNF;
    const int colq = lane & 15;
    const int qk   = lane >> 4;

    // ---- stage + convert W tile (32 rows x 512) into fragment-major LDS
    {
        float ssr[2] = {0.f, 0.f};
        #pragma unroll
        for (int i = 0; i < 4; ++i) {
            const int rb  = i >> 1;
            const int ko  = (i & 1) * 8 + wid;
            const int row = c0 + rb * 16 + colq;       // colq == t&15 here
            const float* src = w + (size_t)row * DK + ko * 32 + qk * 8;
            const f32x4 q0 = __builtin_nontemporal_load((const f32x4*)src);
            const f32x4 q1 = __builtin_nontemporal_load((const f32x4*)(src + 4));
            ssr[rb] += q0.x * q0.x + q0.y * q0.y + q0.z * q0.z + q0.w * q0.w
                     + q1.x * q1.x + q1.y * q1.y + q1.z * q1.z + q1.w * q1.w;
            uint4 p;
            p.x = (uint_t)f2bf(q0.x) | ((uint_t)f2bf(q0.y) << 16);
            p.y = (uint_t)f2bf(q0.z) | ((uint_t)f2bf(q0.w) << 16);
            p.z = (uint_t)f2bf(q1.x) | ((uint_t)f2bf(q1.y) << 16);
            p.w = (uint_t)f2bf(q1.z) | ((uint_t)f2bf(q1.w) << 16);
            *(uint4*)&Bs[i * 4096 + t * 8] = p;
        }
        // sum the 4 qk lane-groups (lane bits 4,5)
        #pragma unroll
        for (int rb = 0; rb < 2; ++rb) {
            ssr[rb] += __shfl_xor(ssr[rb], 16);
            ssr[rb] += __shfl_xor(ssr[rb], 32);
        }
        if (lane < 16) {
            rsum[wid * 32 + lane]      = ssr[0];
            rsum[wid * 32 + 16 + lane] = ssr[1];
        }
    }

    __syncthreads();                   // B tile + rsum partials visible

    // fold 8 wave-partials -> inverse norms in rsum[0..31] (read post-sync2)
    if (t < 32) {
        float s = 0.f;
        #pragma unroll
        for (int wv = 0; wv < 8; ++wv) s += rsum[wv * 32 + t];
        rsum[t] = 1.0f / sqrtf(s);
    }

    const ushort_t* abase = exbF + (size_t)(wid * 4) * 8192 + (size_t)lane * 8;

    f32x4 acc[4][2];
    #pragma unroll
    for (int i = 0; i < 4; ++i)
        #pragma unroll
        for (int j = 0; j < 2; ++j)
            acc[i][j] = (f32x4){0.f, 0.f, 0.f, 0.f};

    // ---- barrier-free K loop: A from global (L2-hot), B from LDS
    const ushort_t* bbase = Bs + (size_t)lane * 8;
    #pragma unroll 2
    for (int ko = 0; ko < 16; ++ko) {
        short8 bfr[2], afr[4];
        #pragma unroll
        for (int nt = 0; nt < 2; ++nt)
            bfr[nt] = *(const short8*)(bbase + nt * 8192 + ko * 512);
        #pragma unroll
        for (int mt = 0; mt < 4; ++mt)
            afr[mt] = *(const short8*)(abase + (size_t)mt * 8192 + ko * 512);
        #pragma unroll
        for (int mt = 0; mt < 4; ++mt)
            #pragma unroll
            for (int nt = 0; nt < 2; ++nt)
                acc[mt][nt] = __builtin_amdgcn_mfma_f32_16x16x32_bf16(
                    afr[mt], bfr[nt], acc[mt][nt], 0, 0, 0);
    }

    __syncthreads();                   // B dead; rn ready; scratch reuse OK

    float rn[2];
    rn[0] = rsum[colq];
    rn[1] = rsum[16 + colq];

    // per-wave 16x35 f32 scratch (2240 B; 8 waves = 17.5 KB <= 32 KB)
    float* Ts = (float*)Bs + wid * (16 * TS_S);

    const int m0 = wid * 64;

    #pragma unroll
    for (int mt = 0; mt < 4; ++mt) {
        // compute logits for this 16x32 sub-tile, scatter to scratch
        #pragma unroll
        for (int rr = 0; rr < 4; ++rr) {
            const int row = m0 + mt * 16 + qk * 4 + rr;
            const float tg = target[row];
            const int   lb = label[row];
            #pragma unroll
            for (int nt = 0; nt < 2; ++nt) {
                const int cc = c0 + nt * 16 + colq;
                const float cosv = acc[mt][nt][rr] * rn[nt];
                const float d  = cosv - tg;
                const float ts = 1.2f * __expf(d * d * -0.5f);
                const float v  = (cc == lb) ? 64.0f * tg
                                            : 64.0f * (ts * cosv + ts - 1.0f);
                Ts[(qk * 4 + rr) * TS_S + nt * 16 + colq] = v;
            }
        }
        // lane-crossing LDS exchange within the wave: force write->read order
        asm volatile("s_waitcnt lgkmcnt(0)" ::: "memory");

        // read back transposed: lane -> row lane>>3 (+8h), cols (lane&7)*4
        #pragma unroll
        for (int h = 0; h < 2; ++h) {
            const int r16 = h * 8 + (lane >> 3);
            const int row = m0 + mt * 16 + r16;
            const int cc4 = (lane & 7) * 4;
            f32x4 v;
            v.x = Ts[r16 * TS_S + cc4 + 0];
            v.y = Ts[r16 * TS_S + cc4 + 1];
            v.z = Ts[r16 * TS_S + cc4 + 2];
            v.w = Ts[r16 * TS_S + cc4 + 3];
            __builtin_nontemporal_store(
                v, (f32x4*)(out + (size_t)row * CTOT + c0 + cc4));
        }
        // guard scratch reuse: reads of mt must complete before mt+1 writes
        asm volatile("s_waitcnt lgkmcnt(0)" ::: "memory");
    }
}

extern "C" void kernel_launch(void* const* d_in, const int* in_sizes, int n_in,
                              void* d_out, int out_size, void* d_ws, size_t ws_size,
                              hipStream_t stream) {
    const float* x     = (const float*)d_in[0];
    const int*   label = (const int*)d_in[1];
    const float* w     = (const float*)d_in[2];
    float* out = (float*)d_out;

    // workspace layout: target (2 KB) + exbF (512 KB)
    float*    target = (float*)d_ws;
    ushort_t* exbF   = (ushort_t*)((char*)d_ws + 2048);

    arc_prep<<<512, 256, 0, stream>>>(x, label, w, target, exbF);
    arc_fused<<<CTOT / BNF, 512, 0, stream>>>(exbF, w, label, target, out);
}